// Round 1
// baseline (755.018 us; speedup 1.0000x reference)
//
#include <hip/hip_runtime.h>
#include <cstdint>
#include <cstddef>

#define BM 128
#define BN 128
#define BK 64

typedef float f32x4 __attribute__((ext_vector_type(4)));
typedef __bf16 bf16x8 __attribute__((ext_vector_type(8)));

__device__ __forceinline__ unsigned short f2bf(float f) {
    unsigned int u = __float_as_uint(f);
    u += 0x7fffu + ((u >> 16) & 1u);   // round-to-nearest-even
    return (unsigned short)(u >> 16);
}

__device__ __forceinline__ void async_copy16(const void* g, void* l) {
    __builtin_amdgcn_global_load_lds(
        (__attribute__((address_space(1))) void*)(g),
        (__attribute__((address_space(3))) void*)(l), 16, 0, 0);
}

// ---------------- elementwise prep kernels ----------------

// x fp32 -> bf16, 8 elems/thread
__global__ void cast_x_kernel(const float* __restrict__ x,
                              unsigned short* __restrict__ o, int n8) {
    int i = blockIdx.x * blockDim.x + threadIdx.x;
    if (i >= n8) return;
    const float4* xv = (const float4*)x;
    float4 a = xv[2 * (size_t)i];
    float4 b = xv[2 * (size_t)i + 1];
    union { unsigned short u[8]; uint4 v; } r;
    r.u[0] = f2bf(a.x); r.u[1] = f2bf(a.y); r.u[2] = f2bf(a.z); r.u[3] = f2bf(a.w);
    r.u[4] = f2bf(b.x); r.u[5] = f2bf(b.y); r.u[6] = f2bf(b.z); r.u[7] = f2bf(b.w);
    ((uint4*)o)[i] = r.v;
}

// int codes [rows, cols] * scales [rows, cols/128] -> bf16, 8 elems/thread
// cols is a power of two (colshift), 8 | 128 so one scale per thread.
__global__ void dequant_kernel(const int* __restrict__ v,
                               const float* __restrict__ s,
                               unsigned short* __restrict__ o,
                               int colshift, int gpr, int n8) {
    int i = blockIdx.x * blockDim.x + threadIdx.x;
    if (i >= n8) return;
    int e = i * 8;
    int row = e >> colshift;
    int col = e & ((1 << colshift) - 1);
    float sc = s[row * gpr + (col >> 7)];
    int4 a = ((const int4*)v)[2 * (size_t)i];
    int4 b = ((const int4*)v)[2 * (size_t)i + 1];
    union { unsigned short u[8]; uint4 x; } r;
    r.u[0] = f2bf(a.x * sc); r.u[1] = f2bf(a.y * sc);
    r.u[2] = f2bf(a.z * sc); r.u[3] = f2bf(a.w * sc);
    r.u[4] = f2bf(b.x * sc); r.u[5] = f2bf(b.y * sc);
    r.u[6] = f2bf(b.z * sc); r.u[7] = f2bf(b.w * sc);
    ((uint4*)o)[i] = r.x;
}

// ---------------- GEMM: out[M,N] = A1[M,K1] * B1[N,K1]^T (+ A2*B2^T) (+bias) ----
// m97-style: 128x128 tile, BK=64, 4 waves (2x2, 64x64 each), 16x16x32 bf16 MFMA,
// global_load_lds width-16 staging, 2-barrier K-loop.
__global__ void __launch_bounds__(256)
gemm_bt_kernel(const __bf16* __restrict__ A1, int lda1, int k1steps,
               const __bf16* __restrict__ B1,
               const __bf16* __restrict__ A2, int lda2, int k2steps,
               const __bf16* __restrict__ B2,
               const float* __restrict__ bias,
               float* __restrict__ outf,
               unsigned short* __restrict__ outb,
               int ldo) {
    __shared__ __bf16 As[BM * BK];   // 16 KB
    __shared__ __bf16 Bs[BN * BK];   // 16 KB

    const int tid  = threadIdx.x;
    const int lane = tid & 63;
    const int wave = tid >> 6;
    const int wm = (wave >> 1) * 64;
    const int wn = (wave & 1) * 64;
    const int mBase = blockIdx.y * BM;
    const int nBase = blockIdx.x * BN;
    const int lrow = lane >> 3;         // 0..7 row within 8-row chunk
    const int lcol = (lane & 7) * 8;    // element offset within 64-wide row

    f32x4 acc[4][4] = {};

    #pragma unroll 1
    for (int phase = 0; phase < 2; ++phase) {
        const __bf16* A = phase ? A2 : A1;
        const __bf16* B = phase ? B2 : B1;
        const int lda    = phase ? lda2 : lda1;
        const int ksteps = phase ? k2steps : k1steps;

        for (int kt = 0; kt < ksteps; ++kt) {
            const int k0 = kt * BK;
            // stage 128x64 A-tile and 128x64 B-tile: each wave fills 4 chunks
            // of 8 rows each (1 KB contiguous LDS = wave-uniform base + lane*16)
            #pragma unroll
            for (int r = 0; r < 4; ++r) {
                const int chunk = wave * 4 + r;          // 0..15
                const int row = chunk * 8 + lrow;        // 0..127
                async_copy16(A + (size_t)(mBase + row) * lda + (k0 + lcol),
                             &As[chunk * 512]);
                async_copy16(B + (size_t)(nBase + row) * lda + (k0 + lcol),
                             &Bs[chunk * 512]);
            }
            __syncthreads();   // compiler emits vmcnt(0) drain before barrier

            #pragma unroll
            for (int ks = 0; ks < 2; ++ks) {
                const int kofs = ks * 32 + (lane >> 4) * 8;
                bf16x8 af[4], bfr[4];
                #pragma unroll
                for (int i = 0; i < 4; ++i)
                    af[i] = *(const bf16x8*)&As[(wm + i * 16 + (lane & 15)) * BK + kofs];
                #pragma unroll
                for (int j = 0; j < 4; ++j)
                    bfr[j] = *(const bf16x8*)&Bs[(wn + j * 16 + (lane & 15)) * BK + kofs];
                #pragma unroll
                for (int i = 0; i < 4; ++i)
                    #pragma unroll
                    for (int j = 0; j < 4; ++j)
                        acc[i][j] = __builtin_amdgcn_mfma_f32_16x16x32_bf16(
                            af[i], bfr[j], acc[i][j], 0, 0, 0);
            }
            __syncthreads();
        }
    }

    // epilogue: C/D layout col = lane&15, row = (lane>>4)*4 + reg
    const int cn = lane & 15;
    const int rg = (lane >> 4) * 4;
    if (outf) {
        #pragma unroll
        for (int j = 0; j < 4; ++j) {
            const int o = nBase + wn + j * 16 + cn;
            const float bv = bias[o];
            #pragma unroll
            for (int i = 0; i < 4; ++i) {
                const int t0 = mBase + wm + i * 16 + rg;
                #pragma unroll
                for (int r = 0; r < 4; ++r)
                    outf[(size_t)(t0 + r) * ldo + o] = acc[i][j][r] + bv;
            }
        }
    } else {
        #pragma unroll
        for (int j = 0; j < 4; ++j) {
            const int o = nBase + wn + j * 16 + cn;
            #pragma unroll
            for (int i = 0; i < 4; ++i) {
                const int t0 = mBase + wm + i * 16 + rg;
                #pragma unroll
                for (int r = 0; r < 4; ++r)
                    outb[(size_t)(t0 + r) * ldo + o] = f2bf(acc[i][j][r]);
            }
        }
    }
}

extern "C" void kernel_launch(void* const* d_in, const int* in_sizes, int n_in,
                              void* d_out, int out_size, void* d_ws, size_t ws_size,
                              hipStream_t stream) {
    const float* x    = (const float*)d_in[0];
    const int*   qv   = (const int*)d_in[1];
    const float* qs   = (const float*)d_in[2];
    const int*   lv   = (const int*)d_in[3];
    const float* ls   = (const float*)d_in[4];
    const int*   rv   = (const int*)d_in[5];
    const float* rs   = (const float*)d_in[6];
    const float* bias = (const float*)d_in[7];
    float* out = (float*)d_out;

    const int T = 8192, DI = 4096, DO = 4096, R = 256;

    // workspace layout (all 16B-aligned; total ~104 MiB)
    char* ws = (char*)d_ws;
    unsigned short* xb = (unsigned short*)(ws);                    // 8192x4096 bf16 = 64 MiB
    unsigned short* Qd = (unsigned short*)(ws + 67108864);         // 4096x4096 bf16 = 32 MiB
    unsigned short* Rd = (unsigned short*)(ws + 100663296);        //  256x4096 bf16 =  2 MiB
    unsigned short* Ld = (unsigned short*)(ws + 102760448);        // 4096x 256 bf16 =  2 MiB
    unsigned short* xr = (unsigned short*)(ws + 104857600);        // 8192x 256 bf16 =  4 MiB

    {   // cast x -> bf16
        int n8 = T * DI / 8;
        cast_x_kernel<<<(n8 + 255) / 256, 256, 0, stream>>>(x, xb, n8);
    }
    {   // dequant Q [4096,4096]
        int n8 = DO * DI / 8;
        dequant_kernel<<<(n8 + 255) / 256, 256, 0, stream>>>(qv, qs, Qd, 12, DI / 128, n8);
    }
    {   // dequant L [4096,256]
        int n8 = DO * R / 8;
        dequant_kernel<<<(n8 + 255) / 256, 256, 0, stream>>>(lv, ls, Ld, 8, R / 128, n8);
    }
    {   // dequant R [256,4096]
        int n8 = R * DI / 8;
        dequant_kernel<<<(n8 + 255) / 256, 256, 0, stream>>>(rv, rs, Rd, 12, DI / 128, n8);
    }
    {   // gemm1: xr[T,R] = xb @ Rd^T   (bf16 output, no bias)
        dim3 g(R / BN, T / BM);
        gemm_bt_kernel<<<g, 256, 0, stream>>>(
            (const __bf16*)xb, DI, DI / BK, (const __bf16*)Rd,
            nullptr, 0, 0, nullptr,
            nullptr, nullptr, xr, R);
    }
    {   // gemm2: out[T,DO] = xb @ Qd^T + xr @ Ld^T + bias   (fp32 output)
        dim3 g(DO / BN, T / BM);
        gemm_bt_kernel<<<g, 256, 0, stream>>>(
            (const __bf16*)xb, DI, DI / BK, (const __bf16*)Qd,
            (const __bf16*)xr, R, R / BK, (const __bf16*)Ld,
            bias, out, nullptr, DO);
    }
}

// Round 2
// 652.675 us; speedup vs baseline: 1.1568x; 1.1568x over previous
//
#include <hip/hip_runtime.h>
#include <cstdint>
#include <cstddef>

#define BM 128
#define BN 128
#define BK 64

typedef float f32x4 __attribute__((ext_vector_type(4)));
typedef __bf16 bf16x8 __attribute__((ext_vector_type(8)));

__device__ __forceinline__ unsigned short f2bf(float f) {
    unsigned int u = __float_as_uint(f);
    u += 0x7fffu + ((u >> 16) & 1u);   // round-to-nearest-even
    return (unsigned short)(u >> 16);
}

__device__ __forceinline__ void async_copy16(const void* g, void* l) {
    __builtin_amdgcn_global_load_lds(
        (__attribute__((address_space(1))) void*)(g),
        (__attribute__((address_space(3))) void*)(l), 16, 0, 0);
}

// ---------------- elementwise prep kernels ----------------

__global__ void cast_x_kernel(const float* __restrict__ x,
                              unsigned short* __restrict__ o, int n8) {
    int i = blockIdx.x * blockDim.x + threadIdx.x;
    if (i >= n8) return;
    const float4* xv = (const float4*)x;
    float4 a = xv[2 * (size_t)i];
    float4 b = xv[2 * (size_t)i + 1];
    union { unsigned short u[8]; uint4 v; } r;
    r.u[0] = f2bf(a.x); r.u[1] = f2bf(a.y); r.u[2] = f2bf(a.z); r.u[3] = f2bf(a.w);
    r.u[4] = f2bf(b.x); r.u[5] = f2bf(b.y); r.u[6] = f2bf(b.z); r.u[7] = f2bf(b.w);
    ((uint4*)o)[i] = r.v;
}

__global__ void dequant_kernel(const int* __restrict__ v,
                               const float* __restrict__ s,
                               unsigned short* __restrict__ o,
                               int colshift, int gpr, int n8) {
    int i = blockIdx.x * blockDim.x + threadIdx.x;
    if (i >= n8) return;
    int e = i * 8;
    int row = e >> colshift;
    int col = e & ((1 << colshift) - 1);
    float sc = s[row * gpr + (col >> 7)];
    int4 a = ((const int4*)v)[2 * (size_t)i];
    int4 b = ((const int4*)v)[2 * (size_t)i + 1];
    union { unsigned short u[8]; uint4 x; } r;
    r.u[0] = f2bf(a.x * sc); r.u[1] = f2bf(a.y * sc);
    r.u[2] = f2bf(a.z * sc); r.u[3] = f2bf(a.w * sc);
    r.u[4] = f2bf(b.x * sc); r.u[5] = f2bf(b.y * sc);
    r.u[6] = f2bf(b.z * sc); r.u[7] = f2bf(b.w * sc);
    ((uint4*)o)[i] = r.x;
}

// ---------------- GEMM: out[M,N] = A1*B1^T (+ A2*B2^T) (+bias) ----------------
// 128x128 tile, BK=64, 4 waves (2x2, 64x64 each), 16x16x32 bf16 MFMA,
// global_load_lds width-16 staging, XOR-swizzled LDS (chunk' = chunk ^ (row&7))
// to break the 128B-row-stride 16-way bank conflict (R1: 1.07e8 conflict cyc).
__global__ void __launch_bounds__(256)
gemm_bt_kernel(const __bf16* __restrict__ A1, int lda1, int k1steps,
               const __bf16* __restrict__ B1,
               const __bf16* __restrict__ A2, int lda2, int k2steps,
               const __bf16* __restrict__ B2,
               const float* __restrict__ bias,
               float* __restrict__ outf,
               unsigned short* __restrict__ outb,
               int ldo) {
    __shared__ __bf16 As[BM * BK];   // 16 KB
    __shared__ __bf16 Bs[BN * BK];   // 16 KB

    const int tid  = threadIdx.x;
    const int lane = tid & 63;
    const int wave = tid >> 6;
    const int wm = (wave >> 1) * 64;
    const int wn = (wave & 1) * 64;
    const int mBase = blockIdx.y * BM;
    const int nBase = blockIdx.x * BN;
    const int lrow = lane >> 3;                          // 0..7 row in 8-row chunk
    // swizzled global chunk: data for global chunk c lands at LDS chunk c^(row&7)
    const int lcol = (((lane & 7) ^ lrow) & 7) * 8;      // element offset in 64-row

    f32x4 acc[4][4] = {};

    #pragma unroll 1
    for (int phase = 0; phase < 2; ++phase) {
        const __bf16* A = phase ? A2 : A1;
        const __bf16* B = phase ? B2 : B1;
        const int lda    = phase ? lda2 : lda1;
        const int ksteps = phase ? k2steps : k1steps;

        for (int kt = 0; kt < ksteps; ++kt) {
            const int k0 = kt * BK;
            #pragma unroll
            for (int r = 0; r < 4; ++r) {
                const int chunk = wave * 4 + r;          // 0..15
                const int row = chunk * 8 + lrow;        // 0..127
                async_copy16(A + (size_t)(mBase + row) * lda + (k0 + lcol),
                             &As[chunk * 512]);
                async_copy16(B + (size_t)(nBase + row) * lda + (k0 + lcol),
                             &Bs[chunk * 512]);
            }
            __syncthreads();

            #pragma unroll
            for (int ks = 0; ks < 2; ++ks) {
                const int kofs = ks * 32 + (lane >> 4) * 8;   // multiple of 8
                const int swz = kofs >> 3;                    // chunk index 0..7
                bf16x8 af[4], bfr[4];
                #pragma unroll
                for (int i = 0; i < 4; ++i) {
                    const int m = wm + i * 16 + (lane & 15);
                    af[i] = *(const bf16x8*)&As[m * BK + (((swz ^ m) & 7) << 3)];
                }
                #pragma unroll
                for (int j = 0; j < 4; ++j) {
                    const int n = wn + j * 16 + (lane & 15);
                    bfr[j] = *(const bf16x8*)&Bs[n * BK + (((swz ^ n) & 7) << 3)];
                }
                #pragma unroll
                for (int i = 0; i < 4; ++i)
                    #pragma unroll
                    for (int j = 0; j < 4; ++j)
                        acc[i][j] = __builtin_amdgcn_mfma_f32_16x16x32_bf16(
                            af[i], bfr[j], acc[i][j], 0, 0, 0);
            }
            __syncthreads();
        }
    }

    // epilogue: C/D layout col = lane&15, row = (lane>>4)*4 + reg
    const int cn = lane & 15;
    const int rg = (lane >> 4) * 4;
    if (outf) {
        #pragma unroll
        for (int j = 0; j < 4; ++j) {
            const int o = nBase + wn + j * 16 + cn;
            const float bv = bias[o];
            #pragma unroll
            for (int i = 0; i < 4; ++i) {
                const int t0 = mBase + wm + i * 16 + rg;
                #pragma unroll
                for (int r = 0; r < 4; ++r)
                    outf[(size_t)(t0 + r) * ldo + o] = acc[i][j][r] + bv;
            }
        }
    } else {
        #pragma unroll
        for (int j = 0; j < 4; ++j) {
            const int o = nBase + wn + j * 16 + cn;
            #pragma unroll
            for (int i = 0; i < 4; ++i) {
                const int t0 = mBase + wm + i * 16 + rg;
                #pragma unroll
                for (int r = 0; r < 4; ++r)
                    outb[(size_t)(t0 + r) * ldo + o] = f2bf(acc[i][j][r]);
            }
        }
    }
}

extern "C" void kernel_launch(void* const* d_in, const int* in_sizes, int n_in,
                              void* d_out, int out_size, void* d_ws, size_t ws_size,
                              hipStream_t stream) {
    const float* x    = (const float*)d_in[0];
    const int*   qv   = (const int*)d_in[1];
    const float* qs   = (const float*)d_in[2];
    const int*   lv   = (const int*)d_in[3];
    const float* ls   = (const float*)d_in[4];
    const int*   rv   = (const int*)d_in[5];
    const float* rs   = (const float*)d_in[6];
    const float* bias = (const float*)d_in[7];
    float* out = (float*)d_out;

    const int T = 8192, DI = 4096, DO = 4096, R = 256;

    char* ws = (char*)d_ws;
    unsigned short* xb = (unsigned short*)(ws);                    // 8192x4096 bf16 = 64 MiB
    unsigned short* Qd = (unsigned short*)(ws + 67108864);         // 4096x4096 bf16 = 32 MiB
    unsigned short* Rd = (unsigned short*)(ws + 100663296);        //  256x4096 bf16 =  2 MiB
    unsigned short* Ld = (unsigned short*)(ws + 102760448);        // 4096x 256 bf16 =  2 MiB
    unsigned short* xr = (unsigned short*)(ws + 104857600);        // 8192x 256 bf16 =  4 MiB

    {
        int n8 = T * DI / 8;
        cast_x_kernel<<<(n8 + 255) / 256, 256, 0, stream>>>(x, xb, n8);
    }
    {
        int n8 = DO * DI / 8;
        dequant_kernel<<<(n8 + 255) / 256, 256, 0, stream>>>(qv, qs, Qd, 12, DI / 128, n8);
    }
    {
        int n8 = DO * R / 8;
        dequant_kernel<<<(n8 + 255) / 256, 256, 0, stream>>>(lv, ls, Ld, 8, R / 128, n8);
    }
    {
        int n8 = R * DI / 8;
        dequant_kernel<<<(n8 + 255) / 256, 256, 0, stream>>>(rv, rs, Rd, 12, DI / 128, n8);
    }
    {   // gemm1: xr[T,R] = xb @ Rd^T
        dim3 g(R / BN, T / BM);
        gemm_bt_kernel<<<g, 256, 0, stream>>>(
            (const __bf16*)xb, DI, DI / BK, (const __bf16*)Rd,
            nullptr, 0, 0, nullptr,
            nullptr, nullptr, xr, R);
    }
    {   // gemm2: out[T,DO] = xb @ Qd^T + xr @ Ld^T + bias
        dim3 g(DO / BN, T / BM);
        gemm_bt_kernel<<<g, 256, 0, stream>>>(
            (const __bf16*)xb, DI, DI / BK, (const __bf16*)Qd,
            (const __bf16*)xr, R, R / BK, (const __bf16*)Ld,
            bias, out, nullptr, DO);
    }
}